// Round 14
// baseline (1223.708 us; speedup 1.0000x reference)
//
#include <hip/hip_runtime.h>
#include <hip/hip_bf16.h>

typedef __hip_bfloat16 bf16;
typedef __attribute__((ext_vector_type(8))) short short8;
typedef __attribute__((ext_vector_type(4))) float f32x4;

#define B_SZ 2
#define L_SEQ 512
#define VOCAB 512
#define D_MODEL 768
#define N_LAYERS 12
#define D_STATE 16
#define D_CONV 4
#define D_INNER 1536
#define DT_RANK 48
#define M_ROWS 1024
#define XDBL_C 80

#define SDG 8
#define SNCH 32
#define SCL 16

#define LDPAD64 72

__device__ __forceinline__ float silu_f(float x) {
    return x / (1.f + expf(-x));
}

__device__ __forceinline__ float b2f(bf16 x) { return __bfloat162float(x); }

__device__ __forceinline__ float bs2f(short s) {
    union { unsigned int u; float f; } cv;
    cv.u = ((unsigned int)(unsigned short)s) << 16;
    return cv.f;
}

__device__ __forceinline__ short f2bs(float x) {
    bf16 t = __float2bfloat16(x);
    return *reinterpret_cast<short*>(&t);
}

__device__ __forceinline__ void cv8(const float* s, short* d) {
    float4 a = *(const float4*)s;
    float4 b = *(const float4*)(s + 4);
    short8 v;
    v[0] = f2bs(a.x); v[1] = f2bs(a.y); v[2] = f2bs(a.z); v[3] = f2bs(a.w);
    v[4] = f2bs(b.x); v[5] = f2bs(b.y); v[6] = f2bs(b.z); v[7] = f2bs(b.w);
    *(short8*)d = v;
}

// all weight conversions in one dispatch; 16 elems/thread (64B read, 32B write)
__global__ __launch_bounds__(256) void to_bf16_all(
    const float* s0, bf16* d0, int e0,
    const float* s1, bf16* d1, int e1,
    const float* s2, bf16* d2, int e2,
    const float* s3, bf16* d3, int e3,
    const float* s4, bf16* d4, int e4)
{
    int i = blockIdx.x * 256 + threadIdx.x;
    const float* s; bf16* d; int base;
    if      (i < e0) { s = s0; d = d0; base = 0;  }
    else if (i < e1) { s = s1; d = d1; base = e0; }
    else if (i < e2) { s = s2; d = d2; base = e1; }
    else if (i < e3) { s = s3; d = d3; base = e2; }
    else if (i < e4) { s = s4; d = d4; base = e3; }
    else return;
    size_t j = (size_t)(i - base) * 16;
    cv8(s + j, (short*)d + j);
    cv8(s + j + 8, (short*)d + j + 8);
}

// 128x64 tile (M=128, N=64), BK=64, 4 waves (2m x 2n of 64x32). bf16 out.
// Requires M % 128 == 0, N % 64 == 0, K % 64 == 0.
__global__ __launch_bounds__(256) void gemm128b(
    const bf16* __restrict__ A, int lda,
    const bf16* __restrict__ W, int ldw,
    bf16* __restrict__ Cb, int N, int K)
{
    __shared__ short As[128 * LDPAD64];
    __shared__ short Ws[64 * LDPAD64];
    int t = threadIdx.x;
    int m0 = blockIdx.y * 128, n0 = blockIdx.x * 64;
    int wave = t >> 6, lane = t & 63;
    int wr = wave >> 1, wc = wave & 1;          // wave tile 64m x 32n
    int lrow = lane & 15, lk = lane >> 4;
    int ar = t >> 1, ac = (t & 1) * 32;         // A staging: 4 chunks
    int wrw = t >> 2, wcc = (t & 3) * 16;       // W staging: 2 chunks

    const bf16* Ab = A + (size_t)(m0 + ar) * lda + ac;
    const bf16* Wb = W + (size_t)(n0 + wrw) * ldw + wcc;

    f32x4 acc[4][2] = {};

    short8 ra[4], rw[2];
#pragma unroll
    for (int j = 0; j < 4; j++) ra[j] = *(const short8*)(Ab + 8 * j);
#pragma unroll
    for (int j = 0; j < 2; j++) rw[j] = *(const short8*)(Wb + 8 * j);

    for (int k0 = 0; k0 < K; k0 += 64) {
#pragma unroll
        for (int j = 0; j < 4; j++) *(short8*)(&As[ar * LDPAD64 + ac + 8 * j]) = ra[j];
#pragma unroll
        for (int j = 0; j < 2; j++) *(short8*)(&Ws[wrw * LDPAD64 + wcc + 8 * j]) = rw[j];
        __syncthreads();

        int kn = k0 + 64;
        if (kn < K) {
#pragma unroll
            for (int j = 0; j < 4; j++) ra[j] = *(const short8*)(Ab + kn + 8 * j);
#pragma unroll
            for (int j = 0; j < 2; j++) rw[j] = *(const short8*)(Wb + kn + 8 * j);
        }

#pragma unroll
        for (int k8 = 0; k8 < 2; k8++) {
            short8 af[4], bw[2];
#pragma unroll
            for (int i = 0; i < 4; i++)
                af[i] = *(const short8*)(&As[(wr * 64 + i * 16 + lrow) * LDPAD64 + k8 * 32 + lk * 8]);
#pragma unroll
            for (int j = 0; j < 2; j++)
                bw[j] = *(const short8*)(&Ws[(wc * 32 + j * 16 + lrow) * LDPAD64 + k8 * 32 + lk * 8]);
#pragma unroll
            for (int i = 0; i < 4; i++)
#pragma unroll
                for (int j = 0; j < 2; j++)
                    acc[i][j] = __builtin_amdgcn_mfma_f32_16x16x32_bf16(af[i], bw[j], acc[i][j], 0, 0, 0);
        }
        __syncthreads();
    }

#pragma unroll
    for (int i = 0; i < 4; i++)
#pragma unroll
        for (int j = 0; j < 2; j++) {
            int col = n0 + wc * 32 + j * 16 + lrow;
#pragma unroll
            for (int r = 0; r < 4; r++) {
                int row = m0 + wr * 64 + i * 16 + lk * 4 + r;
                Cb[(size_t)row * N + col] = __float2bfloat16(acc[i][j][r]);
            }
        }
}

// 128x64 tile, BK=64, split-K partials (fp32). klen % 64 == 0.
__global__ __launch_bounds__(256) void gemm128k(
    const bf16* __restrict__ A, int lda,
    const bf16* __restrict__ W, int ldw,
    float* __restrict__ Cpart, int klen, int N)
{
    __shared__ short As[128 * LDPAD64];
    __shared__ short Ws[64 * LDPAD64];
    int t = threadIdx.x;
    int m0 = blockIdx.y * 128, n0 = blockIdx.x * 64;
    int ks = blockIdx.z * klen;
    Cpart += (size_t)blockIdx.z * M_ROWS * N;
    int wave = t >> 6, lane = t & 63;
    int wr = wave >> 1, wc = wave & 1;
    int lrow = lane & 15, lk = lane >> 4;
    int ar = t >> 1, ac = (t & 1) * 32;
    int wrw = t >> 2, wcc = (t & 3) * 16;

    const bf16* Ab = A + (size_t)(m0 + ar) * lda + ks + ac;
    const bf16* Wb = W + (size_t)(n0 + wrw) * ldw + ks + wcc;

    f32x4 acc[4][2] = {};

    short8 ra[4], rw[2];
#pragma unroll
    for (int j = 0; j < 4; j++) ra[j] = *(const short8*)(Ab + 8 * j);
#pragma unroll
    for (int j = 0; j < 2; j++) rw[j] = *(const short8*)(Wb + 8 * j);

    for (int k0 = 0; k0 < klen; k0 += 64) {
#pragma unroll
        for (int j = 0; j < 4; j++) *(short8*)(&As[ar * LDPAD64 + ac + 8 * j]) = ra[j];
#pragma unroll
        for (int j = 0; j < 2; j++) *(short8*)(&Ws[wrw * LDPAD64 + wcc + 8 * j]) = rw[j];
        __syncthreads();

        int kn = k0 + 64;
        if (kn < klen) {
#pragma unroll
            for (int j = 0; j < 4; j++) ra[j] = *(const short8*)(Ab + kn + 8 * j);
#pragma unroll
            for (int j = 0; j < 2; j++) rw[j] = *(const short8*)(Wb + kn + 8 * j);
        }

#pragma unroll
        for (int k8 = 0; k8 < 2; k8++) {
            short8 af[4], bw[2];
#pragma unroll
            for (int i = 0; i < 4; i++)
                af[i] = *(const short8*)(&As[(wr * 64 + i * 16 + lrow) * LDPAD64 + k8 * 32 + lk * 8]);
#pragma unroll
            for (int j = 0; j < 2; j++)
                bw[j] = *(const short8*)(&Ws[(wc * 32 + j * 16 + lrow) * LDPAD64 + k8 * 32 + lk * 8]);
#pragma unroll
            for (int i = 0; i < 4; i++)
#pragma unroll
                for (int j = 0; j < 2; j++)
                    acc[i][j] = __builtin_amdgcn_mfma_f32_16x16x32_bf16(af[i], bw[j], acc[i][j], 0, 0, 0);
        }
        __syncthreads();
    }

#pragma unroll
    for (int i = 0; i < 4; i++)
#pragma unroll
        for (int j = 0; j < 2; j++) {
            int col = n0 + wc * 32 + j * 16 + lrow;
#pragma unroll
            for (int r = 0; r < 4; r++) {
                int row = m0 + wr * 64 + i * 16 + lk * 4 + r;
                Cpart[(size_t)row * N + col] = acc[i][j][r];
            }
        }
}

// 64x64x64 split-K (head): grid must give >= ~1 block/CU
__global__ __launch_bounds__(256) void gemm64k(
    const bf16* __restrict__ A, int lda,
    const bf16* __restrict__ W, int ldw,
    float* __restrict__ Cpart, int klen, int N)
{
    __shared__ short As[64 * LDPAD64];
    __shared__ short Ws[64 * LDPAD64];
    int t = threadIdx.x;
    int m0 = blockIdx.y * 64, n0 = blockIdx.x * 64;
    int ks = blockIdx.z * klen;
    Cpart += (size_t)blockIdx.z * M_ROWS * N;
    int wave = t >> 6, lane = t & 63;
    int wr = wave >> 1, wc = wave & 1;
    int lrow = lane & 15, lk = lane >> 4;
    int srow = t >> 2, scol = (t & 3) * 8;

    const bf16* Arow = A + (size_t)(m0 + srow) * lda + ks;
    const bf16* Wrow = W + (size_t)(n0 + srow) * ldw + ks;

    f32x4 acc[2][2] = {};

    short8 ra0 = *(const short8*)(Arow + scol);
    short8 ra1 = *(const short8*)(Arow + scol + 32);
    short8 rw0 = *(const short8*)(Wrow + scol);
    short8 rw1 = *(const short8*)(Wrow + scol + 32);

    for (int k0 = 0; k0 < klen; k0 += 64) {
        *(short8*)(&As[srow * LDPAD64 + scol]) = ra0;
        *(short8*)(&As[srow * LDPAD64 + scol + 32]) = ra1;
        *(short8*)(&Ws[srow * LDPAD64 + scol]) = rw0;
        *(short8*)(&Ws[srow * LDPAD64 + scol + 32]) = rw1;
        __syncthreads();

        int kn = k0 + 64;
        if (kn < klen) {
            ra0 = *(const short8*)(Arow + kn + scol);
            ra1 = *(const short8*)(Arow + kn + scol + 32);
            rw0 = *(const short8*)(Wrow + kn + scol);
            rw1 = *(const short8*)(Wrow + kn + scol + 32);
        }

#pragma unroll
        for (int k8 = 0; k8 < 2; k8++) {
            short8 af[2], bw[2];
#pragma unroll
            for (int i = 0; i < 2; i++) {
                af[i] = *(const short8*)(&As[(wr * 32 + i * 16 + lrow) * LDPAD64 + k8 * 32 + lk * 8]);
                bw[i] = *(const short8*)(&Ws[(wc * 32 + i * 16 + lrow) * LDPAD64 + k8 * 32 + lk * 8]);
            }
#pragma unroll
            for (int i = 0; i < 2; i++)
#pragma unroll
                for (int j = 0; j < 2; j++)
                    acc[i][j] = __builtin_amdgcn_mfma_f32_16x16x32_bf16(af[i], bw[j], acc[i][j], 0, 0, 0);
        }
        __syncthreads();
    }

#pragma unroll
    for (int i = 0; i < 2; i++)
#pragma unroll
        for (int j = 0; j < 2; j++) {
            int col = n0 + wc * 32 + j * 16 + lrow;
#pragma unroll
            for (int r = 0; r < 4; r++) {
                int row = m0 + wr * 32 + i * 16 + lk * 4 + r;
                Cpart[(size_t)row * N + col] = acc[i][j][r];
            }
        }
}

__global__ __launch_bounds__(256) void reduce_out_kernel(
    const float* __restrict__ Cp, float* __restrict__ x, bf16* __restrict__ xb)
{
    const int n = M_ROWS * D_MODEL;
    int i = blockIdx.x * 256 + threadIdx.x;
    if (i >= n / 4) return;
    float4 s0 = ((const float4*)Cp)[i];
    float4 s1 = ((const float4*)(Cp + n))[i];
    float4 s2 = ((const float4*)(Cp + 2 * n))[i];
    float4 s3 = ((const float4*)(Cp + 3 * n))[i];
    float4 xv = ((float4*)x)[i];
    xv.x += s0.x + s1.x + s2.x + s3.x;
    xv.y += s0.y + s1.y + s2.y + s3.y;
    xv.z += s0.z + s1.z + s2.z + s3.z;
    xv.w += s0.w + s1.w + s2.w + s3.w;
    ((float4*)x)[i] = xv;
    short* xbs = (short*)xb + (size_t)i * 4;
    xbs[0] = f2bs(xv.x); xbs[1] = f2bs(xv.y); xbs[2] = f2bs(xv.z); xbs[3] = f2bs(xv.w);
}

__global__ __launch_bounds__(256) void reduce_head_kernel(
    const float* __restrict__ Cp, const float* __restrict__ head_b,
    float* __restrict__ logits)
{
    const int n = M_ROWS * VOCAB;
    int i = blockIdx.x * 256 + threadIdx.x;
    if (i >= n / 4) return;
    float4 s0 = ((const float4*)Cp)[i];
    float4 s1 = ((const float4*)(Cp + n))[i];
    float4 bv = ((const float4*)head_b)[i % (VOCAB / 4)];
    float4 o;
    o.x = s0.x + s1.x + bv.x;
    o.y = s0.y + s1.y + bv.y;
    o.z = s0.z + s1.z + bv.z;
    o.w = s0.w + s1.w + bv.w;
    ((float4*)logits)[i] = o;
}

// Fused conv+silu + xp-proj. 2 rows/block (512 blocks). Wave-parallel dots.
__global__ __launch_bounds__(256) void convxp2_kernel(
    const bf16* __restrict__ xr, const float* __restrict__ conv_w,
    const float* __restrict__ conv_b, const bf16* __restrict__ xp_wb,
    bf16* __restrict__ R, bf16* __restrict__ xdbl)
{
    __shared__ short us[2][1544];
    int t = threadIdx.x;
    int r0 = blockIdx.x * 2;

    for (int i = 0; i < 12; i++) {
        int e = i * 256 + t;
        int rr = (e >= 1536) ? 1 : 0;
        int d = e - rr * 1536;
        int m = r0 + rr;
        int l = m & (L_SEQ - 1);
        float acc = conv_b[d];
#pragma unroll
        for (int j = 0; j < D_CONV; j++) {
            int ls = l - (D_CONV - 1) + j;
            if (ls >= 0)
                acc += conv_w[d * D_CONV + j] *
                       b2f(xr[(size_t)(m - (D_CONV - 1) + j) * (2 * D_INNER) + d]);
        }
        short sv = f2bs(silu_f(acc));
        us[rr][d] = sv;
        *((short*)R + (size_t)m * D_INNER + d) = sv;
    }
    __syncthreads();

    int wave = t >> 6, lane = t & 63;
    for (int ni = 0; ni < 20; ni++) {
        int n = wave * 20 + ni;
        const short* wrow = (const short*)xp_wb + (size_t)n * D_INNER;
        short8 w0 = *(const short8*)(wrow + lane * 8);
        short8 w1 = *(const short8*)(wrow + lane * 8 + 512);
        short8 w2 = *(const short8*)(wrow + lane * 8 + 1024);
#pragma unroll
        for (int r = 0; r < 2; r++) {
            const short* ur = us[r];
            short8 u0 = *(const short8*)(ur + lane * 8);
            short8 u1 = *(const short8*)(ur + lane * 8 + 512);
            short8 u2 = *(const short8*)(ur + lane * 8 + 1024);
            float p = 0.f;
#pragma unroll
            for (int q = 0; q < 8; q++) {
                p += bs2f(u0[q]) * bs2f(w0[q]);
                p += bs2f(u1[q]) * bs2f(w1[q]);
                p += bs2f(u2[q]) * bs2f(w2[q]);
            }
#pragma unroll
            for (int s = 1; s < 64; s <<= 1)
                p += __shfl_xor(p, s);
            if (lane == 0)
                xdbl[(size_t)(r0 + r) * XDBL_C + n] = __float2bfloat16(p);
        }
    }
}

// Fused dt-proj + chunked scan + gate (384 blocks). exp-chain fast path.
__global__ __launch_bounds__(256) void scan_fused(
    bf16* xr, const bf16* __restrict__ R, const bf16* __restrict__ xdbl,
    const bf16* __restrict__ dt_wb, const float* __restrict__ dt_b,
    const float* __restrict__ A_log, const float* __restrict__ Dp)
{
    __shared__ short us[L_SEQ][9];
    __shared__ short dss[L_SEQ][9];
    __shared__ float Pl[SNCH][SDG][17];
    __shared__ float Ql[SNCH][SDG][17];

    int t = threadIdx.x;
    int bg = blockIdx.x;
    int b  = bg / (D_INNER / SDG);
    int dg = bg % (D_INNER / SDG);
    int d_base = dg * SDG;

    for (int i = 0; i < L_SEQ * SDG / 256; i++) {
        int e = i * 256 + t;
        int ml = e >> 3, dl = e & 7;
        int d = d_base + dl;
        int m = b * L_SEQ + ml;
        us[ml][dl] = *((const short*)R + (size_t)m * D_INNER + d);
        const short* xrow = (const short*)xdbl + (size_t)m * XDBL_C;
        const short* wrow = (const short*)dt_wb + (size_t)d * DT_RANK;
        float acc = dt_b[d];
#pragma unroll
        for (int k8 = 0; k8 < DT_RANK / 8; k8++) {
            short8 a8 = *(const short8*)(xrow + k8 * 8);
            short8 w8 = *(const short8*)(wrow + k8 * 8);
#pragma unroll
            for (int q = 0; q < 8; q++)
                acc += bs2f(a8[q]) * bs2f(w8[q]);
        }
        acc = (acc > 20.f) ? acc : log1pf(expf(acc));
        dss[ml][dl] = f2bs(acc);
    }

    int dl_ = t & (SDG - 1);
    int c   = t >> 3;
    int d   = d_base + dl_;

    float An[D_STATE], h[D_STATE], Pp[D_STATE];
    bool chain = true;
#pragma unroll
    for (int n = 0; n < D_STATE; n++) {
        An[n] = -expf(A_log[d * D_STATE + n]);
        chain = chain && (fabsf(An[n] + (float)(n + 1)) < 1e-3f * (n + 1));
        h[n] = 0.f;
        Pp[n] = 1.f;
    }
    __syncthreads();

    int ml0 = c * SCL;
    size_t mg0 = (size_t)b * L_SEQ + ml0;

    if (chain) {
        float sdl = 0.f;
        for (int i = 0; i < SCL; i++) {
            int ml = ml0 + i;
            float dlv = bs2f(dss[ml][dl_]);
            float uvv = bs2f(us[ml][dl_]);
            float duv = dlv * uvv;
            sdl += dlv;
            const short8* brow = (const short8*)((const short*)xdbl + (mg0 + i) * XDBL_C + DT_RANK);
            short8 b0 = brow[0], b1 = brow[1];
            float e1 = expf(-dlv), ap = e1;
#pragma unroll
            for (int n = 0; n < D_STATE; n++) {
                float Bn = bs2f(n < 8 ? b0[n] : b1[n - 8]);
                h[n] = ap * h[n] + duv * Bn;
                ap *= e1;
            }
        }
        float E = expf(-sdl), Ep = E;
#pragma unroll
        for (int n = 0; n < D_STATE; n++) { Pp[n] = Ep; Ep *= E; }
    } else {
        for (int i = 0; i < SCL; i++) {
            int ml = ml0 + i;
            float dlv = bs2f(dss[ml][dl_]);
            float uvv = bs2f(us[ml][dl_]);
            float duv = dlv * uvv;
            const short8* brow = (const short8*)((const short*)xdbl + (mg0 + i) * XDBL_C + DT_RANK);
            short8 b0 = brow[0], b1 = brow[1];
#pragma unroll
            for (int n = 0; n < D_STATE; n++) {
                float a = expf(dlv * An[n]);
                Pp[n] *= a;
                float Bn = bs2f(n < 8 ? b0[n] : b1[n - 8]);
                h[n] = a * h[n] + duv * Bn;
            }
        }
    }
#pragma unroll
    for (int n = 0; n < D_STATE; n++) {
        Pl[c][dl_][n] = Pp[n];
        Ql[c][dl_][n] = h[n];
    }
    __syncthreads();

    if (t < SDG * D_STATE) {
        int dd = t & (SDG - 1);
        int nn = t >> 3;
        float h0 = 0.f;
        for (int cc = 0; cc < SNCH; cc++) {
            float p = Pl[cc][dd][nn];
            float q = Ql[cc][dd][nn];
            Pl[cc][dd][nn] = h0;
            h0 = p * h0 + q;
        }
    }
    __syncthreads();

    float Dv = Dp[d];
#pragma unroll
    for (int n = 0; n < D_STATE; n++) h[n] = Pl[c][dl_][n];
    for (int i = 0; i < SCL; i++) {
        int ml = ml0 + i;
        size_t m = mg0 + i;
        float dlv = bs2f(dss[ml][dl_]);
        float uvv = bs2f(us[ml][dl_]);
        float duv = dlv * uvv;
        const short8* brow = (const short8*)((const short*)xdbl + m * XDBL_C + DT_RANK);
        short8 b0 = brow[0], b1 = brow[1];
        short8 c0 = brow[2], c1 = brow[3];
        float y = 0.f;
        if (chain) {
            float e1 = expf(-dlv), ap = e1;
#pragma unroll
            for (int n = 0; n < D_STATE; n++) {
                float Bn = bs2f(n < 8 ? b0[n] : b1[n - 8]);
                float Cn = bs2f(n < 8 ? c0[n] : c1[n - 8]);
                h[n] = ap * h[n] + duv * Bn;
                y += h[n] * Cn;
                ap *= e1;
            }
        } else {
#pragma unroll
            for (int n = 0; n < D_STATE; n++) {
                float a = expf(dlv * An[n]);
                float Bn = bs2f(n < 8 ? b0[n] : b1[n - 8]);
                float Cn = bs2f(n < 8 ? c0[n] : c1[n - 8]);
                h[n] = a * h[n] + duv * Bn;
                y += h[n] * Cn;
            }
        }
        y += uvv * Dv;
        float r = b2f(xr[m * (2 * D_INNER) + D_INNER + d]);
        xr[m * (2 * D_INNER) + d] = __float2bfloat16(y * silu_f(r));
    }
}

__global__ __launch_bounds__(256) void embed_kernel(
    const float* __restrict__ emb, const int* __restrict__ ids,
    float* __restrict__ x, bf16* __restrict__ xb)
{
    int idx = blockIdx.x * 256 + threadIdx.x;
    if (idx >= M_ROWS * D_MODEL / 4) return;
    int m = idx / (D_MODEL / 4);
    int k4 = idx % (D_MODEL / 4);
    float4 v = ((const float4*)(emb + (size_t)ids[m] * D_MODEL))[k4];
    ((float4*)x)[idx] = v;
    short* xbs = (short*)xb + (size_t)idx * 4;
    xbs[0] = f2bs(v.x); xbs[1] = f2bs(v.y); xbs[2] = f2bs(v.z); xbs[3] = f2bs(v.w);
}

__global__ __launch_bounds__(256) void ln_kernel(
    const float* __restrict__ x, const float* __restrict__ gam,
    const float* __restrict__ bet, float* __restrict__ hidden_f32,
    bf16* __restrict__ hidden_bf)
{
    int row = blockIdx.x;
    const float* xr = x + (size_t)row * D_MODEL;
    float s = 0.f, s2 = 0.f;
    for (int i = threadIdx.x; i < D_MODEL; i += 256) {
        float v = xr[i];
        s += v; s2 += v * v;
    }
    __shared__ float red[18];
#pragma unroll
    for (int off = 32; off; off >>= 1) {
        s += __shfl_down(s, off);
        s2 += __shfl_down(s2, off);
    }
    int wid = threadIdx.x / 64, lane = threadIdx.x % 64;
    if (lane == 0) { red[wid * 2] = s; red[wid * 2 + 1] = s2; }
    __syncthreads();
    if (threadIdx.x == 0) {
        float ts = 0.f, ts2 = 0.f;
        for (int w = 0; w < 4; w++) { ts += red[w * 2]; ts2 += red[w * 2 + 1]; }
        red[16] = ts; red[17] = ts2;
    }
    __syncthreads();
    float mean = red[16] / D_MODEL;
    float var = red[17] / D_MODEL - mean * mean;
    float inv = rsqrtf(var + 1e-5f);
    for (int i = threadIdx.x; i < D_MODEL; i += 256) {
        float v = (xr[i] - mean) * inv * gam[i] + bet[i];
        hidden_f32[(size_t)row * D_MODEL + i] = v;
        hidden_bf[(size_t)row * D_MODEL + i] = __float2bfloat16(v);
    }
}

extern "C" void kernel_launch(void* const* d_in, const int* in_sizes, int n_in,
                              void* d_out, int out_size, void* d_ws, size_t ws_size,
                              hipStream_t stream) {
    const float* emb    = (const float*)d_in[0];
    const float* in_w   = (const float*)d_in[1];
    const float* conv_w = (const float*)d_in[2];
    const float* conv_b = (const float*)d_in[3];
    const float* xp_w   = (const float*)d_in[4];
    const float* dt_w   = (const float*)d_in[5];
    const float* dt_b   = (const float*)d_in[6];
    const float* A_log  = (const float*)d_in[7];
    const float* Dp     = (const float*)d_in[8];
    const float* out_w  = (const float*)d_in[9];
    const float* ln_g   = (const float*)d_in[10];
    const float* ln_b   = (const float*)d_in[11];
    const float* head_w = (const float*)d_in[12];
    const float* head_b = (const float*)d_in[13];
    const int*   ids    = (const int*)d_in[14];

    float* out_logits = (float*)d_out;
    float* out_hidden = (float*)d_out + (size_t)M_ROWS * VOCAB;

    char* base = (char*)d_ws;
    float* x       = (float*)(base);                 // 3,145,728
    bf16*  xb      = (bf16*) (base + 3145728);       // 1,572,864
    bf16*  xr      = (bf16*) (base + 4718592);       // 6,291,456
    bf16*  R       = (bf16*) (base + 11010048);      // 3,145,728
    bf16*  xdbl    = (bf16*) (base + 14155776);      //   163,840
    bf16*  hidb    = (bf16*) (base + 14319616);      // 1,572,864
    bf16*  in_wb   = (bf16*) (base + 15892480);      // 56,623,104
    bf16*  xp_wb   = (bf16*) (base + 72515584);      //  2,949,120
    bf16*  dt_wb   = (bf16*) (base + 75464704);      //  1,769,472
    bf16*  out_wb  = (bf16*) (base + 77234176);      // 28,311,552
    bf16*  head_wb = (bf16*) (base + 105545728);     //    786,432
    float* Cp      = (float*)(base + 106332160);     // 12,582,912

    // merged weight conversion: cumulative 16-elem-group ends
    {
        const int e0 = 28311552 / 16;                 // in_w
        const int e1 = e0 + 1474560 / 16;             // + xp_w
        const int e2 = e1 + 884736 / 16;              // + dt_w
        const int e3 = e2 + 14155776 / 16;            // + out_w
        const int e4 = e3 + 393216 / 16;              // + head_w
        to_bf16_all<<<(e4 + 255) / 256, 256, 0, stream>>>(
            in_w, in_wb, e0, xp_w, xp_wb, e1, dt_w, dt_wb, e2,
            out_w, out_wb, e3, head_w, head_wb, e4);
    }

    embed_kernel<<<(M_ROWS * D_MODEL / 4 + 255) / 256, 256, 0, stream>>>(emb, ids, x, xb);

    for (int i = 0; i < N_LAYERS; i++) {
        const bf16*  in_wb_i  = in_wb  + (size_t)i * 2 * D_INNER * D_MODEL;
        const float* conv_w_i = conv_w + (size_t)i * D_INNER * D_CONV;
        const float* conv_b_i = conv_b + (size_t)i * D_INNER;
        const bf16*  xp_wb_i  = xp_wb  + (size_t)i * XDBL_C * D_INNER;
        const bf16*  dt_wb_i  = dt_wb  + (size_t)i * D_INNER * DT_RANK;
        const float* dt_b_i   = dt_b   + (size_t)i * D_INNER;
        const float* A_log_i  = A_log  + (size_t)i * D_INNER * D_STATE;
        const float* Dp_i     = Dp     + (size_t)i * D_INNER;
        const bf16*  out_wb_i = out_wb + (size_t)i * D_MODEL * D_INNER;

        // 1. xr = xb @ in_w^T  (48 x 8 = 384 blocks, M128 tile)
        gemm128b<<<dim3(2 * D_INNER / 64, M_ROWS / 128), 256, 0, stream>>>(
            xb, D_MODEL, in_wb_i, D_MODEL, xr, 2 * D_INNER, D_MODEL);

        // 2. fused conv+silu+xp: u -> R, xdbl  (512 blocks)
        convxp2_kernel<<<M_ROWS / 2, 256, 0, stream>>>(
            xr, conv_w_i, conv_b_i, xp_wb_i, R, xdbl);

        // 3. fused dt+scan+gate -> g into xr[:, 0:1536]  (384 blocks)
        scan_fused<<<B_SZ * (D_INNER / SDG), 256, 0, stream>>>(
            xr, R, xdbl, dt_wb_i, dt_b_i, A_log_i, Dp_i);

        // 4. out-proj split-K x4, M128 tile  (12 x 8 x 4 = 384 blocks)
        gemm128k<<<dim3(D_MODEL / 64, M_ROWS / 128, 4), 256, 0, stream>>>(
            xr, 2 * D_INNER, out_wb_i, D_INNER, Cp, 384, D_MODEL);

        // 5. x += sum(partials); xb = bf16(x)
        reduce_out_kernel<<<(M_ROWS * D_MODEL / 4 + 255) / 256, 256, 0, stream>>>(
            Cp, x, xb);
    }

    ln_kernel<<<M_ROWS, 256, 0, stream>>>(x, ln_g, ln_b, out_hidden, hidb);

    // head split-K x2  (8 x 16 x 2 = 256 blocks)
    gemm64k<<<dim3(VOCAB / 64, M_ROWS / 64, 2), 256, 0, stream>>>(
        hidb, D_MODEL, head_wb, D_MODEL, Cp, 384, VOCAB);

    reduce_head_kernel<<<(M_ROWS * VOCAB / 4 + 255) / 256, 256, 0, stream>>>(
        Cp, head_b, out_logits);
}

// Round 15
// 1198.955 us; speedup vs baseline: 1.0206x; 1.0206x over previous
//
#include <hip/hip_runtime.h>
#include <hip/hip_bf16.h>

typedef __hip_bfloat16 bf16;
typedef __attribute__((ext_vector_type(8))) short short8;
typedef __attribute__((ext_vector_type(4))) float f32x4;

#define B_SZ 2
#define L_SEQ 512
#define VOCAB 512
#define D_MODEL 768
#define N_LAYERS 12
#define D_STATE 16
#define D_CONV 4
#define D_INNER 1536
#define DT_RANK 48
#define M_ROWS 1024
#define XDBL_C 80

#define SDG 8
#define SNCH 32
#define SCL 16

#define LDPAD64 72

__device__ __forceinline__ float silu_f(float x) {
    return x / (1.f + expf(-x));
}

__device__ __forceinline__ float b2f(bf16 x) { return __bfloat162float(x); }

__device__ __forceinline__ float bs2f(short s) {
    union { unsigned int u; float f; } cv;
    cv.u = ((unsigned int)(unsigned short)s) << 16;
    return cv.f;
}

__device__ __forceinline__ short f2bs(float x) {
    bf16 t = __float2bfloat16(x);
    return *reinterpret_cast<short*>(&t);
}

__device__ __forceinline__ void cv8(const float* s, short* d) {
    float4 a = *(const float4*)s;
    float4 b = *(const float4*)(s + 4);
    short8 v;
    v[0] = f2bs(a.x); v[1] = f2bs(a.y); v[2] = f2bs(a.z); v[3] = f2bs(a.w);
    v[4] = f2bs(b.x); v[5] = f2bs(b.y); v[6] = f2bs(b.z); v[7] = f2bs(b.w);
    *(short8*)d = v;
}

// merged weight conversion; 16 elems/thread with per-instruction-contiguous
// writes: thread (q, lane) handles elems q*4096 + lane*8 and +2048.
// Segment sizes must be multiples of 4096 elems (all are).
__global__ __launch_bounds__(256) void to_bf16_all(
    const float* s0, bf16* d0, int e0,
    const float* s1, bf16* d1, int e1,
    const float* s2, bf16* d2, int e2,
    const float* s3, bf16* d3, int e3,
    const float* s4, bf16* d4, int e4)
{
    int i = blockIdx.x * 256 + threadIdx.x;
    const float* s; bf16* d; int base;
    if      (i < e0) { s = s0; d = d0; base = 0;  }
    else if (i < e1) { s = s1; d = d1; base = e0; }
    else if (i < e2) { s = s2; d = d2; base = e1; }
    else if (i < e3) { s = s3; d = d3; base = e2; }
    else if (i < e4) { s = s4; d = d4; base = e3; }
    else return;
    int r = i - base;
    size_t j = (size_t)(r >> 8) * 4096 + (size_t)(r & 255) * 8;
    cv8(s + j, (short*)d + j);
    cv8(s + j + 2048, (short*)d + j + 2048);
}

// 64x64x64 tile (BK=64), 4 waves, padded LDS, register-prefetch. bf16 out.
// Requires M,N % 64 == 0, K % 64 == 0.
__global__ __launch_bounds__(256) void gemm64b(
    const bf16* __restrict__ A, int lda,
    const bf16* __restrict__ W, int ldw,
    bf16* __restrict__ Cb, int N, int K)
{
    __shared__ short As[64 * LDPAD64];
    __shared__ short Ws[64 * LDPAD64];
    int t = threadIdx.x;
    int m0 = blockIdx.y * 64, n0 = blockIdx.x * 64;
    int wave = t >> 6, lane = t & 63;
    int wr = wave >> 1, wc = wave & 1;
    int lrow = lane & 15, lk = lane >> 4;
    int srow = t >> 2, scol = (t & 3) * 8;

    const bf16* Arow = A + (size_t)(m0 + srow) * lda;
    const bf16* Wrow = W + (size_t)(n0 + srow) * ldw;

    f32x4 acc[2][2] = {};

    short8 ra0 = *(const short8*)(Arow + scol);
    short8 ra1 = *(const short8*)(Arow + scol + 32);
    short8 rw0 = *(const short8*)(Wrow + scol);
    short8 rw1 = *(const short8*)(Wrow + scol + 32);

    for (int k0 = 0; k0 < K; k0 += 64) {
        *(short8*)(&As[srow * LDPAD64 + scol]) = ra0;
        *(short8*)(&As[srow * LDPAD64 + scol + 32]) = ra1;
        *(short8*)(&Ws[srow * LDPAD64 + scol]) = rw0;
        *(short8*)(&Ws[srow * LDPAD64 + scol + 32]) = rw1;
        __syncthreads();

        int kn = k0 + 64;
        if (kn < K) {
            ra0 = *(const short8*)(Arow + kn + scol);
            ra1 = *(const short8*)(Arow + kn + scol + 32);
            rw0 = *(const short8*)(Wrow + kn + scol);
            rw1 = *(const short8*)(Wrow + kn + scol + 32);
        }

#pragma unroll
        for (int k8 = 0; k8 < 2; k8++) {
            short8 af[2], bw[2];
#pragma unroll
            for (int i = 0; i < 2; i++) {
                af[i] = *(const short8*)(&As[(wr * 32 + i * 16 + lrow) * LDPAD64 + k8 * 32 + lk * 8]);
                bw[i] = *(const short8*)(&Ws[(wc * 32 + i * 16 + lrow) * LDPAD64 + k8 * 32 + lk * 8]);
            }
#pragma unroll
            for (int i = 0; i < 2; i++)
#pragma unroll
                for (int j = 0; j < 2; j++)
                    acc[i][j] = __builtin_amdgcn_mfma_f32_16x16x32_bf16(af[i], bw[j], acc[i][j], 0, 0, 0);
        }
        __syncthreads();
    }

#pragma unroll
    for (int i = 0; i < 2; i++)
#pragma unroll
        for (int j = 0; j < 2; j++) {
            int col = n0 + wc * 32 + j * 16 + lrow;
#pragma unroll
            for (int r = 0; r < 4; r++) {
                int row = m0 + wr * 32 + i * 16 + lk * 4 + r;
                Cb[(size_t)row * N + col] = __float2bfloat16(acc[i][j][r]);
            }
        }
}

// BK=64 split-K partials: blockIdx.z selects [z*klen, (z+1)*klen); fp32 partials.
__global__ __launch_bounds__(256) void gemm64k(
    const bf16* __restrict__ A, int lda,
    const bf16* __restrict__ W, int ldw,
    float* __restrict__ Cpart, int klen, int N)
{
    __shared__ short As[64 * LDPAD64];
    __shared__ short Ws[64 * LDPAD64];
    int t = threadIdx.x;
    int m0 = blockIdx.y * 64, n0 = blockIdx.x * 64;
    int ks = blockIdx.z * klen;
    Cpart += (size_t)blockIdx.z * M_ROWS * N;
    int wave = t >> 6, lane = t & 63;
    int wr = wave >> 1, wc = wave & 1;
    int lrow = lane & 15, lk = lane >> 4;
    int srow = t >> 2, scol = (t & 3) * 8;

    const bf16* Arow = A + (size_t)(m0 + srow) * lda + ks;
    const bf16* Wrow = W + (size_t)(n0 + srow) * ldw + ks;

    f32x4 acc[2][2] = {};

    short8 ra0 = *(const short8*)(Arow + scol);
    short8 ra1 = *(const short8*)(Arow + scol + 32);
    short8 rw0 = *(const short8*)(Wrow + scol);
    short8 rw1 = *(const short8*)(Wrow + scol + 32);

    for (int k0 = 0; k0 < klen; k0 += 64) {
        *(short8*)(&As[srow * LDPAD64 + scol]) = ra0;
        *(short8*)(&As[srow * LDPAD64 + scol + 32]) = ra1;
        *(short8*)(&Ws[srow * LDPAD64 + scol]) = rw0;
        *(short8*)(&Ws[srow * LDPAD64 + scol + 32]) = rw1;
        __syncthreads();

        int kn = k0 + 64;
        if (kn < klen) {
            ra0 = *(const short8*)(Arow + kn + scol);
            ra1 = *(const short8*)(Arow + kn + scol + 32);
            rw0 = *(const short8*)(Wrow + kn + scol);
            rw1 = *(const short8*)(Wrow + kn + scol + 32);
        }

#pragma unroll
        for (int k8 = 0; k8 < 2; k8++) {
            short8 af[2], bw[2];
#pragma unroll
            for (int i = 0; i < 2; i++) {
                af[i] = *(const short8*)(&As[(wr * 32 + i * 16 + lrow) * LDPAD64 + k8 * 32 + lk * 8]);
                bw[i] = *(const short8*)(&Ws[(wc * 32 + i * 16 + lrow) * LDPAD64 + k8 * 32 + lk * 8]);
            }
#pragma unroll
            for (int i = 0; i < 2; i++)
#pragma unroll
                for (int j = 0; j < 2; j++)
                    acc[i][j] = __builtin_amdgcn_mfma_f32_16x16x32_bf16(af[i], bw[j], acc[i][j], 0, 0, 0);
        }
        __syncthreads();
    }

#pragma unroll
    for (int i = 0; i < 2; i++)
#pragma unroll
        for (int j = 0; j < 2; j++) {
            int col = n0 + wc * 32 + j * 16 + lrow;
#pragma unroll
            for (int r = 0; r < 4; r++) {
                int row = m0 + wr * 32 + i * 16 + lk * 4 + r;
                Cpart[(size_t)row * N + col] = acc[i][j][r];
            }
        }
}

__global__ __launch_bounds__(256) void reduce_out_kernel(
    const float* __restrict__ Cp, float* __restrict__ x, bf16* __restrict__ xb)
{
    const int n = M_ROWS * D_MODEL;
    int i = blockIdx.x * 256 + threadIdx.x;
    if (i >= n / 4) return;
    float4 s0 = ((const float4*)Cp)[i];
    float4 s1 = ((const float4*)(Cp + n))[i];
    float4 s2 = ((const float4*)(Cp + 2 * n))[i];
    float4 s3 = ((const float4*)(Cp + 3 * n))[i];
    float4 xv = ((float4*)x)[i];
    xv.x += s0.x + s1.x + s2.x + s3.x;
    xv.y += s0.y + s1.y + s2.y + s3.y;
    xv.z += s0.z + s1.z + s2.z + s3.z;
    xv.w += s0.w + s1.w + s2.w + s3.w;
    ((float4*)x)[i] = xv;
    short* xbs = (short*)xb + (size_t)i * 4;
    xbs[0] = f2bs(xv.x); xbs[1] = f2bs(xv.y); xbs[2] = f2bs(xv.z); xbs[3] = f2bs(xv.w);
}

__global__ __launch_bounds__(256) void reduce_head_kernel(
    const float* __restrict__ Cp, const float* __restrict__ head_b,
    float* __restrict__ logits)
{
    const int n = M_ROWS * VOCAB;
    int i = blockIdx.x * 256 + threadIdx.x;
    if (i >= n / 4) return;
    float4 s0 = ((const float4*)Cp)[i];
    float4 s1 = ((const float4*)(Cp + n))[i];
    float4 bv = ((const float4*)head_b)[i % (VOCAB / 4)];
    float4 o;
    o.x = s0.x + s1.x + bv.x;
    o.y = s0.y + s1.y + bv.y;
    o.z = s0.z + s1.z + bv.z;
    o.w = s0.w + s1.w + bv.w;
    ((float4*)logits)[i] = o;
}

// Fused conv+silu + xp-proj. 2 rows/block (512 blocks). Wave-parallel dots.
__global__ __launch_bounds__(256) void convxp2_kernel(
    const bf16* __restrict__ xr, const float* __restrict__ conv_w,
    const float* __restrict__ conv_b, const bf16* __restrict__ xp_wb,
    bf16* __restrict__ R, bf16* __restrict__ xdbl)
{
    __shared__ short us[2][1544];
    int t = threadIdx.x;
    int r0 = blockIdx.x * 2;

    for (int i = 0; i < 12; i++) {
        int e = i * 256 + t;
        int rr = (e >= 1536) ? 1 : 0;
        int d = e - rr * 1536;
        int m = r0 + rr;
        int l = m & (L_SEQ - 1);
        float acc = conv_b[d];
#pragma unroll
        for (int j = 0; j < D_CONV; j++) {
            int ls = l - (D_CONV - 1) + j;
            if (ls >= 0)
                acc += conv_w[d * D_CONV + j] *
                       b2f(xr[(size_t)(m - (D_CONV - 1) + j) * (2 * D_INNER) + d]);
        }
        short sv = f2bs(silu_f(acc));
        us[rr][d] = sv;
        *((short*)R + (size_t)m * D_INNER + d) = sv;
    }
    __syncthreads();

    int wave = t >> 6, lane = t & 63;
    for (int ni = 0; ni < 20; ni++) {
        int n = wave * 20 + ni;
        const short* wrow = (const short*)xp_wb + (size_t)n * D_INNER;
        short8 w0 = *(const short8*)(wrow + lane * 8);
        short8 w1 = *(const short8*)(wrow + lane * 8 + 512);
        short8 w2 = *(const short8*)(wrow + lane * 8 + 1024);
#pragma unroll
        for (int r = 0; r < 2; r++) {
            const short* ur = us[r];
            short8 u0 = *(const short8*)(ur + lane * 8);
            short8 u1 = *(const short8*)(ur + lane * 8 + 512);
            short8 u2 = *(const short8*)(ur + lane * 8 + 1024);
            float p = 0.f;
#pragma unroll
            for (int q = 0; q < 8; q++) {
                p += bs2f(u0[q]) * bs2f(w0[q]);
                p += bs2f(u1[q]) * bs2f(w1[q]);
                p += bs2f(u2[q]) * bs2f(w2[q]);
            }
#pragma unroll
            for (int s = 1; s < 64; s <<= 1)
                p += __shfl_xor(p, s);
            if (lane == 0)
                xdbl[(size_t)(r0 + r) * XDBL_C + n] = __float2bfloat16(p);
        }
    }
}

// Fused dt-proj + chunked scan + gate (384 blocks). exp-chain fast path.
__global__ __launch_bounds__(256) void scan_fused(
    bf16* xr, const bf16* __restrict__ R, const bf16* __restrict__ xdbl,
    const bf16* __restrict__ dt_wb, const float* __restrict__ dt_b,
    const float* __restrict__ A_log, const float* __restrict__ Dp)
{
    __shared__ short us[L_SEQ][9];
    __shared__ short dss[L_SEQ][9];
    __shared__ float Pl[SNCH][SDG][17];
    __shared__ float Ql[SNCH][SDG][17];

    int t = threadIdx.x;
    int bg = blockIdx.x;
    int b  = bg / (D_INNER / SDG);
    int dg = bg % (D_INNER / SDG);
    int d_base = dg * SDG;

    for (int i = 0; i < L_SEQ * SDG / 256; i++) {
        int e = i * 256 + t;
        int ml = e >> 3, dl = e & 7;
        int d = d_base + dl;
        int m = b * L_SEQ + ml;
        us[ml][dl] = *((const short*)R + (size_t)m * D_INNER + d);
        const short* xrow = (const short*)xdbl + (size_t)m * XDBL_C;
        const short* wrow = (const short*)dt_wb + (size_t)d * DT_RANK;
        float acc = dt_b[d];
#pragma unroll
        for (int k8 = 0; k8 < DT_RANK / 8; k8++) {
            short8 a8 = *(const short8*)(xrow + k8 * 8);
            short8 w8 = *(const short8*)(wrow + k8 * 8);
#pragma unroll
            for (int q = 0; q < 8; q++)
                acc += bs2f(a8[q]) * bs2f(w8[q]);
        }
        acc = (acc > 20.f) ? acc : log1pf(expf(acc));
        dss[ml][dl] = f2bs(acc);
    }

    int dl_ = t & (SDG - 1);
    int c   = t >> 3;
    int d   = d_base + dl_;

    float An[D_STATE], h[D_STATE], Pp[D_STATE];
    bool chain = true;
#pragma unroll
    for (int n = 0; n < D_STATE; n++) {
        An[n] = -expf(A_log[d * D_STATE + n]);
        chain = chain && (fabsf(An[n] + (float)(n + 1)) < 1e-3f * (n + 1));
        h[n] = 0.f;
        Pp[n] = 1.f;
    }
    __syncthreads();

    int ml0 = c * SCL;
    size_t mg0 = (size_t)b * L_SEQ + ml0;

    if (chain) {
        float sdl = 0.f;
        for (int i = 0; i < SCL; i++) {
            int ml = ml0 + i;
            float dlv = bs2f(dss[ml][dl_]);
            float uvv = bs2f(us[ml][dl_]);
            float duv = dlv * uvv;
            sdl += dlv;
            const short8* brow = (const short8*)((const short*)xdbl + (mg0 + i) * XDBL_C + DT_RANK);
            short8 b0 = brow[0], b1 = brow[1];
            float e1 = expf(-dlv), ap = e1;
#pragma unroll
            for (int n = 0; n < D_STATE; n++) {
                float Bn = bs2f(n < 8 ? b0[n] : b1[n - 8]);
                h[n] = ap * h[n] + duv * Bn;
                ap *= e1;
            }
        }
        float E = expf(-sdl), Ep = E;
#pragma unroll
        for (int n = 0; n < D_STATE; n++) { Pp[n] = Ep; Ep *= E; }
    } else {
        for (int i = 0; i < SCL; i++) {
            int ml = ml0 + i;
            float dlv = bs2f(dss[ml][dl_]);
            float uvv = bs2f(us[ml][dl_]);
            float duv = dlv * uvv;
            const short8* brow = (const short8*)((const short*)xdbl + (mg0 + i) * XDBL_C + DT_RANK);
            short8 b0 = brow[0], b1 = brow[1];
#pragma unroll
            for (int n = 0; n < D_STATE; n++) {
                float a = expf(dlv * An[n]);
                Pp[n] *= a;
                float Bn = bs2f(n < 8 ? b0[n] : b1[n - 8]);
                h[n] = a * h[n] + duv * Bn;
            }
        }
    }
#pragma unroll
    for (int n = 0; n < D_STATE; n++) {
        Pl[c][dl_][n] = Pp[n];
        Ql[c][dl_][n] = h[n];
    }
    __syncthreads();

    if (t < SDG * D_STATE) {
        int dd = t & (SDG - 1);
        int nn = t >> 3;
        float h0 = 0.f;
        for (int cc = 0; cc < SNCH; cc++) {
            float p = Pl[cc][dd][nn];
            float q = Ql[cc][dd][nn];
            Pl[cc][dd][nn] = h0;
            h0 = p * h0 + q;
        }
    }
    __syncthreads();

    float Dv = Dp[d];
#pragma unroll
    for (int n = 0; n < D_STATE; n++) h[n] = Pl[c][dl_][n];
    for (int i = 0; i < SCL; i++) {
        int ml = ml0 + i;
        size_t m = mg0 + i;
        float dlv = bs2f(dss[ml][dl_]);
        float uvv = bs2f(us[ml][dl_]);
        float duv = dlv * uvv;
        const short8* brow = (const short8*)((const short*)xdbl + m * XDBL_C + DT_RANK);
        short8 b0 = brow[0], b1 = brow[1];
        short8 c0 = brow[2], c1 = brow[3];
        float y = 0.f;
        if (chain) {
            float e1 = expf(-dlv), ap = e1;
#pragma unroll
            for (int n = 0; n < D_STATE; n++) {
                float Bn = bs2f(n < 8 ? b0[n] : b1[n - 8]);
                float Cn = bs2f(n < 8 ? c0[n] : c1[n - 8]);
                h[n] = ap * h[n] + duv * Bn;
                y += h[n] * Cn;
                ap *= e1;
            }
        } else {
#pragma unroll
            for (int n = 0; n < D_STATE; n++) {
                float a = expf(dlv * An[n]);
                float Bn = bs2f(n < 8 ? b0[n] : b1[n - 8]);
                float Cn = bs2f(n < 8 ? c0[n] : c1[n - 8]);
                h[n] = a * h[n] + duv * Bn;
                y += h[n] * Cn;
            }
        }
        y += uvv * Dv;
        float r = b2f(xr[m * (2 * D_INNER) + D_INNER + d]);
        xr[m * (2 * D_INNER) + d] = __float2bfloat16(y * silu_f(r));
    }
}

__global__ __launch_bounds__(256) void embed_kernel(
    const float* __restrict__ emb, const int* __restrict__ ids,
    float* __restrict__ x, bf16* __restrict__ xb)
{
    int idx = blockIdx.x * 256 + threadIdx.x;
    if (idx >= M_ROWS * D_MODEL / 4) return;
    int m = idx / (D_MODEL / 4);
    int k4 = idx % (D_MODEL / 4);
    float4 v = ((const float4*)(emb + (size_t)ids[m] * D_MODEL))[k4];
    ((float4*)x)[idx] = v;
    short* xbs = (short*)xb + (size_t)idx * 4;
    xbs[0] = f2bs(v.x); xbs[1] = f2bs(v.y); xbs[2] = f2bs(v.z); xbs[3] = f2bs(v.w);
}

__global__ __launch_bounds__(256) void ln_kernel(
    const float* __restrict__ x, const float* __restrict__ gam,
    const float* __restrict__ bet, float* __restrict__ hidden_f32,
    bf16* __restrict__ hidden_bf)
{
    int row = blockIdx.x;
    const float* xr = x + (size_t)row * D_MODEL;
    float s = 0.f, s2 = 0.f;
    for (int i = threadIdx.x; i < D_MODEL; i += 256) {
        float v = xr[i];
        s += v; s2 += v * v;
    }
    __shared__ float red[18];
#pragma unroll
    for (int off = 32; off; off >>= 1) {
        s += __shfl_down(s, off);
        s2 += __shfl_down(s2, off);
    }
    int wid = threadIdx.x / 64, lane = threadIdx.x % 64;
    if (lane == 0) { red[wid * 2] = s; red[wid * 2 + 1] = s2; }
    __syncthreads();
    if (threadIdx.x == 0) {
        float ts = 0.f, ts2 = 0.f;
        for (int w = 0; w < 4; w++) { ts += red[w * 2]; ts2 += red[w * 2 + 1]; }
        red[16] = ts; red[17] = ts2;
    }
    __syncthreads();
    float mean = red[16] / D_MODEL;
    float var = red[17] / D_MODEL - mean * mean;
    float inv = rsqrtf(var + 1e-5f);
    for (int i = threadIdx.x; i < D_MODEL; i += 256) {
        float v = (xr[i] - mean) * inv * gam[i] + bet[i];
        hidden_f32[(size_t)row * D_MODEL + i] = v;
        hidden_bf[(size_t)row * D_MODEL + i] = __float2bfloat16(v);
    }
}

extern "C" void kernel_launch(void* const* d_in, const int* in_sizes, int n_in,
                              void* d_out, int out_size, void* d_ws, size_t ws_size,
                              hipStream_t stream) {
    const float* emb    = (const float*)d_in[0];
    const float* in_w   = (const float*)d_in[1];
    const float* conv_w = (const float*)d_in[2];
    const float* conv_b = (const float*)d_in[3];
    const float* xp_w   = (const float*)d_in[4];
    const float* dt_w   = (const float*)d_in[5];
    const float* dt_b   = (const float*)d_in[6];
    const float* A_log  = (const float*)d_in[7];
    const float* Dp     = (const float*)d_in[8];
    const float* out_w  = (const float*)d_in[9];
    const float* ln_g   = (const float*)d_in[10];
    const float* ln_b   = (const float*)d_in[11];
    const float* head_w = (const float*)d_in[12];
    const float* head_b = (const float*)d_in[13];
    const int*   ids    = (const int*)d_in[14];

    float* out_logits = (float*)d_out;
    float* out_hidden = (float*)d_out + (size_t)M_ROWS * VOCAB;

    char* base = (char*)d_ws;
    float* x       = (float*)(base);                 // 3,145,728
    bf16*  xb      = (bf16*) (base + 3145728);       // 1,572,864
    bf16*  xr      = (bf16*) (base + 4718592);       // 6,291,456
    bf16*  R       = (bf16*) (base + 11010048);      // 3,145,728
    bf16*  xdbl    = (bf16*) (base + 14155776);      //   163,840
    bf16*  hidb    = (bf16*) (base + 14319616);      // 1,572,864
    bf16*  in_wb   = (bf16*) (base + 15892480);      // 56,623,104
    bf16*  xp_wb   = (bf16*) (base + 72515584);      //  2,949,120
    bf16*  dt_wb   = (bf16*) (base + 75464704);      //  1,769,472
    bf16*  out_wb  = (bf16*) (base + 77234176);      // 28,311,552
    bf16*  head_wb = (bf16*) (base + 105545728);     //    786,432
    float* Cp      = (float*)(base + 106332160);     // 12,582,912

    // merged weight conversion: cumulative 16-elem-group ends
    {
        const int e0 = 28311552 / 16;                 // in_w
        const int e1 = e0 + 1474560 / 16;             // + xp_w
        const int e2 = e1 + 884736 / 16;              // + dt_w
        const int e3 = e2 + 14155776 / 16;            // + out_w
        const int e4 = e3 + 393216 / 16;              // + head_w
        to_bf16_all<<<(e4 + 255) / 256, 256, 0, stream>>>(
            in_w, in_wb, e0, xp_w, xp_wb, e1, dt_w, dt_wb, e2,
            out_w, out_wb, e3, head_w, head_wb, e4);
    }

    embed_kernel<<<(M_ROWS * D_MODEL / 4 + 255) / 256, 256, 0, stream>>>(emb, ids, x, xb);

    for (int i = 0; i < N_LAYERS; i++) {
        const bf16*  in_wb_i  = in_wb  + (size_t)i * 2 * D_INNER * D_MODEL;
        const float* conv_w_i = conv_w + (size_t)i * D_INNER * D_CONV;
        const float* conv_b_i = conv_b + (size_t)i * D_INNER;
        const bf16*  xp_wb_i  = xp_wb  + (size_t)i * XDBL_C * D_INNER;
        const bf16*  dt_wb_i  = dt_wb  + (size_t)i * D_INNER * DT_RANK;
        const float* dt_b_i   = dt_b   + (size_t)i * D_INNER;
        const float* A_log_i  = A_log  + (size_t)i * D_INNER * D_STATE;
        const float* Dp_i     = Dp     + (size_t)i * D_INNER;
        const bf16*  out_wb_i = out_wb + (size_t)i * D_MODEL * D_INNER;

        // 1. xr = xb @ in_w^T  (768 blocks, BK=64)
        gemm64b<<<dim3(2 * D_INNER / 64, M_ROWS / 64), 256, 0, stream>>>(
            xb, D_MODEL, in_wb_i, D_MODEL, xr, 2 * D_INNER, D_MODEL);

        // 2. fused conv+silu+xp: u -> R, xdbl  (512 blocks)
        convxp2_kernel<<<M_ROWS / 2, 256, 0, stream>>>(
            xr, conv_w_i, conv_b_i, xp_wb_i, R, xdbl);

        // 3. fused dt+scan+gate -> g into xr[:, 0:1536]  (384 blocks)
        scan_fused<<<B_SZ * (D_INNER / SDG), 256, 0, stream>>>(
            xr, R, xdbl, dt_wb_i, dt_b_i, A_log_i, Dp_i);

        // 4. out-proj split-K x4, BK=64  (768 blocks)
        gemm64k<<<dim3(D_MODEL / 64, M_ROWS / 64, 4), 256, 0, stream>>>(
            xr, 2 * D_INNER, out_wb_i, D_INNER, Cp, 384, D_MODEL);

        // 5. x += sum(partials); xb = bf16(x)
        reduce_out_kernel<<<(M_ROWS * D_MODEL / 4 + 255) / 256, 256, 0, stream>>>(
            Cp, x, xb);
    }

    ln_kernel<<<M_ROWS, 256, 0, stream>>>(x, ln_g, ln_b, out_hidden, hidb);

    // head split-K x2  (256 blocks)
    gemm64k<<<dim3(VOCAB / 64, M_ROWS / 64, 2), 256, 0, stream>>>(
        hidb, D_MODEL, head_wb, D_MODEL, Cp, 384, VOCAB);

    reduce_head_kernel<<<(M_ROWS * VOCAB / 4 + 255) / 256, 256, 0, stream>>>(
        Cp, head_b, out_logits);
}

// Round 16
// 1161.917 us; speedup vs baseline: 1.0532x; 1.0319x over previous
//
#include <hip/hip_runtime.h>
#include <hip/hip_bf16.h>

typedef __hip_bfloat16 bf16;
typedef __attribute__((ext_vector_type(8))) short short8;
typedef __attribute__((ext_vector_type(4))) float f32x4;

#define B_SZ 2
#define L_SEQ 512
#define VOCAB 512
#define D_MODEL 768
#define N_LAYERS 12
#define D_STATE 16
#define D_CONV 4
#define D_INNER 1536
#define DT_RANK 48
#define M_ROWS 1024
#define XDBL_C 80

// scan geometry: 4 d-lanes x 64 chunks of 8 steps (768 blocks)
#define SDG 4
#define SNCH 64
#define SCL 8

#define LDPAD64 72

__device__ __forceinline__ float silu_f(float x) {
    return x / (1.f + expf(-x));
}

__device__ __forceinline__ float b2f(bf16 x) { return __bfloat162float(x); }

__device__ __forceinline__ float bs2f(short s) {
    union { unsigned int u; float f; } cv;
    cv.u = ((unsigned int)(unsigned short)s) << 16;
    return cv.f;
}

__device__ __forceinline__ short f2bs(float x) {
    bf16 t = __float2bfloat16(x);
    return *reinterpret_cast<short*>(&t);
}

__device__ __forceinline__ short8 cvt8(float4 a, float4 b) {
    short8 v;
    v[0] = f2bs(a.x); v[1] = f2bs(a.y); v[2] = f2bs(a.z); v[3] = f2bs(a.w);
    v[4] = f2bs(b.x); v[5] = f2bs(b.y); v[6] = f2bs(b.z); v[7] = f2bs(b.w);
    return v;
}

// merged weight conversion; 32 elems/thread, 4 stripes of 2048 elems within an
// 8192-elem block chunk. All 8 float4 loads hoisted (ILP). Segment sizes must
// be multiples of 8192 elems (all are).
__global__ __launch_bounds__(256) void to_bf16_all(
    const float* s0, bf16* d0, int e0,
    const float* s1, bf16* d1, int e1,
    const float* s2, bf16* d2, int e2,
    const float* s3, bf16* d3, int e3,
    const float* s4, bf16* d4, int e4)
{
    int i = blockIdx.x * 256 + threadIdx.x;
    const float* s; bf16* d; int base;
    if      (i < e0) { s = s0; d = d0; base = 0;  }
    else if (i < e1) { s = s1; d = d1; base = e0; }
    else if (i < e2) { s = s2; d = d2; base = e1; }
    else if (i < e3) { s = s3; d = d3; base = e2; }
    else if (i < e4) { s = s4; d = d4; base = e3; }
    else return;
    int r = i - base;
    size_t j = (size_t)(r >> 8) * 8192 + (size_t)(r & 255) * 8;
    const float4* p0 = (const float4*)(s + j);
    const float4* p1 = (const float4*)(s + j + 2048);
    const float4* p2 = (const float4*)(s + j + 4096);
    const float4* p3 = (const float4*)(s + j + 6144);
    float4 a0 = p0[0], b0 = p0[1];
    float4 a1 = p1[0], b1 = p1[1];
    float4 a2 = p2[0], b2 = p2[1];
    float4 a3 = p3[0], b3 = p3[1];
    *(short8*)((short*)d + j)        = cvt8(a0, b0);
    *(short8*)((short*)d + j + 2048) = cvt8(a1, b1);
    *(short8*)((short*)d + j + 4096) = cvt8(a2, b2);
    *(short8*)((short*)d + j + 6144) = cvt8(a3, b3);
}

// 64x64x64 tile (BK=64), 4 waves, padded LDS, register-prefetch. bf16 out.
__global__ __launch_bounds__(256) void gemm64b(
    const bf16* __restrict__ A, int lda,
    const bf16* __restrict__ W, int ldw,
    bf16* __restrict__ Cb, int N, int K)
{
    __shared__ short As[64 * LDPAD64];
    __shared__ short Ws[64 * LDPAD64];
    int t = threadIdx.x;
    int m0 = blockIdx.y * 64, n0 = blockIdx.x * 64;
    int wave = t >> 6, lane = t & 63;
    int wr = wave >> 1, wc = wave & 1;
    int lrow = lane & 15, lk = lane >> 4;
    int srow = t >> 2, scol = (t & 3) * 8;

    const bf16* Arow = A + (size_t)(m0 + srow) * lda;
    const bf16* Wrow = W + (size_t)(n0 + srow) * ldw;

    f32x4 acc[2][2] = {};

    short8 ra0 = *(const short8*)(Arow + scol);
    short8 ra1 = *(const short8*)(Arow + scol + 32);
    short8 rw0 = *(const short8*)(Wrow + scol);
    short8 rw1 = *(const short8*)(Wrow + scol + 32);

    for (int k0 = 0; k0 < K; k0 += 64) {
        *(short8*)(&As[srow * LDPAD64 + scol]) = ra0;
        *(short8*)(&As[srow * LDPAD64 + scol + 32]) = ra1;
        *(short8*)(&Ws[srow * LDPAD64 + scol]) = rw0;
        *(short8*)(&Ws[srow * LDPAD64 + scol + 32]) = rw1;
        __syncthreads();

        int kn = k0 + 64;
        if (kn < K) {
            ra0 = *(const short8*)(Arow + kn + scol);
            ra1 = *(const short8*)(Arow + kn + scol + 32);
            rw0 = *(const short8*)(Wrow + kn + scol);
            rw1 = *(const short8*)(Wrow + kn + scol + 32);
        }

#pragma unroll
        for (int k8 = 0; k8 < 2; k8++) {
            short8 af[2], bw[2];
#pragma unroll
            for (int i = 0; i < 2; i++) {
                af[i] = *(const short8*)(&As[(wr * 32 + i * 16 + lrow) * LDPAD64 + k8 * 32 + lk * 8]);
                bw[i] = *(const short8*)(&Ws[(wc * 32 + i * 16 + lrow) * LDPAD64 + k8 * 32 + lk * 8]);
            }
#pragma unroll
            for (int i = 0; i < 2; i++)
#pragma unroll
                for (int j = 0; j < 2; j++)
                    acc[i][j] = __builtin_amdgcn_mfma_f32_16x16x32_bf16(af[i], bw[j], acc[i][j], 0, 0, 0);
        }
        __syncthreads();
    }

#pragma unroll
    for (int i = 0; i < 2; i++)
#pragma unroll
        for (int j = 0; j < 2; j++) {
            int col = n0 + wc * 32 + j * 16 + lrow;
#pragma unroll
            for (int r = 0; r < 4; r++) {
                int row = m0 + wr * 32 + i * 16 + lk * 4 + r;
                Cb[(size_t)row * N + col] = __float2bfloat16(acc[i][j][r]);
            }
        }
}

// BK=64 split-K partials.
__global__ __launch_bounds__(256) void gemm64k(
    const bf16* __restrict__ A, int lda,
    const bf16* __restrict__ W, int ldw,
    float* __restrict__ Cpart, int klen, int N)
{
    __shared__ short As[64 * LDPAD64];
    __shared__ short Ws[64 * LDPAD64];
    int t = threadIdx.x;
    int m0 = blockIdx.y * 64, n0 = blockIdx.x * 64;
    int ks = blockIdx.z * klen;
    Cpart += (size_t)blockIdx.z * M_ROWS * N;
    int wave = t >> 6, lane = t & 63;
    int wr = wave >> 1, wc = wave & 1;
    int lrow = lane & 15, lk = lane >> 4;
    int srow = t >> 2, scol = (t & 3) * 8;

    const bf16* Arow = A + (size_t)(m0 + srow) * lda + ks;
    const bf16* Wrow = W + (size_t)(n0 + srow) * ldw + ks;

    f32x4 acc[2][2] = {};

    short8 ra0 = *(const short8*)(Arow + scol);
    short8 ra1 = *(const short8*)(Arow + scol + 32);
    short8 rw0 = *(const short8*)(Wrow + scol);
    short8 rw1 = *(const short8*)(Wrow + scol + 32);

    for (int k0 = 0; k0 < klen; k0 += 64) {
        *(short8*)(&As[srow * LDPAD64 + scol]) = ra0;
        *(short8*)(&As[srow * LDPAD64 + scol + 32]) = ra1;
        *(short8*)(&Ws[srow * LDPAD64 + scol]) = rw0;
        *(short8*)(&Ws[srow * LDPAD64 + scol + 32]) = rw1;
        __syncthreads();

        int kn = k0 + 64;
        if (kn < klen) {
            ra0 = *(const short8*)(Arow + kn + scol);
            ra1 = *(const short8*)(Arow + kn + scol + 32);
            rw0 = *(const short8*)(Wrow + kn + scol);
            rw1 = *(const short8*)(Wrow + kn + scol + 32);
        }

#pragma unroll
        for (int k8 = 0; k8 < 2; k8++) {
            short8 af[2], bw[2];
#pragma unroll
            for (int i = 0; i < 2; i++) {
                af[i] = *(const short8*)(&As[(wr * 32 + i * 16 + lrow) * LDPAD64 + k8 * 32 + lk * 8]);
                bw[i] = *(const short8*)(&Ws[(wc * 32 + i * 16 + lrow) * LDPAD64 + k8 * 32 + lk * 8]);
            }
#pragma unroll
            for (int i = 0; i < 2; i++)
#pragma unroll
                for (int j = 0; j < 2; j++)
                    acc[i][j] = __builtin_amdgcn_mfma_f32_16x16x32_bf16(af[i], bw[j], acc[i][j], 0, 0, 0);
        }
        __syncthreads();
    }

#pragma unroll
    for (int i = 0; i < 2; i++)
#pragma unroll
        for (int j = 0; j < 2; j++) {
            int col = n0 + wc * 32 + j * 16 + lrow;
#pragma unroll
            for (int r = 0; r < 4; r++) {
                int row = m0 + wr * 32 + i * 16 + lk * 4 + r;
                Cpart[(size_t)row * N + col] = acc[i][j][r];
            }
        }
}

__global__ __launch_bounds__(256) void reduce_out_kernel(
    const float* __restrict__ Cp, float* __restrict__ x, bf16* __restrict__ xb)
{
    const int n = M_ROWS * D_MODEL;
    int i = blockIdx.x * 256 + threadIdx.x;
    if (i >= n / 4) return;
    float4 s0 = ((const float4*)Cp)[i];
    float4 s1 = ((const float4*)(Cp + n))[i];
    float4 s2 = ((const float4*)(Cp + 2 * n))[i];
    float4 s3 = ((const float4*)(Cp + 3 * n))[i];
    float4 xv = ((float4*)x)[i];
    xv.x += s0.x + s1.x + s2.x + s3.x;
    xv.y += s0.y + s1.y + s2.y + s3.y;
    xv.z += s0.z + s1.z + s2.z + s3.z;
    xv.w += s0.w + s1.w + s2.w + s3.w;
    ((float4*)x)[i] = xv;
    short* xbs = (short*)xb + (size_t)i * 4;
    xbs[0] = f2bs(xv.x); xbs[1] = f2bs(xv.y); xbs[2] = f2bs(xv.z); xbs[3] = f2bs(xv.w);
}

__global__ __launch_bounds__(256) void reduce_head_kernel(
    const float* __restrict__ Cp, const float* __restrict__ head_b,
    float* __restrict__ logits)
{
    const int n = M_ROWS * VOCAB;
    int i = blockIdx.x * 256 + threadIdx.x;
    if (i >= n / 4) return;
    float4 s0 = ((const float4*)Cp)[i];
    float4 s1 = ((const float4*)(Cp + n))[i];
    float4 bv = ((const float4*)head_b)[i % (VOCAB / 4)];
    float4 o;
    o.x = s0.x + s1.x + bv.x;
    o.y = s0.y + s1.y + bv.y;
    o.z = s0.z + s1.z + bv.z;
    o.w = s0.w + s1.w + bv.w;
    ((float4*)logits)[i] = o;
}

// Fused conv+silu + xp-proj. 2 rows/block (512 blocks). Wave-parallel dots.
__global__ __launch_bounds__(256) void convxp2_kernel(
    const bf16* __restrict__ xr, const float* __restrict__ conv_w,
    const float* __restrict__ conv_b, const bf16* __restrict__ xp_wb,
    bf16* __restrict__ R, bf16* __restrict__ xdbl)
{
    __shared__ short us[2][1544];
    int t = threadIdx.x;
    int r0 = blockIdx.x * 2;

    for (int i = 0; i < 12; i++) {
        int e = i * 256 + t;
        int rr = (e >= 1536) ? 1 : 0;
        int d = e - rr * 1536;
        int m = r0 + rr;
        int l = m & (L_SEQ - 1);
        float acc = conv_b[d];
#pragma unroll
        for (int j = 0; j < D_CONV; j++) {
            int ls = l - (D_CONV - 1) + j;
            if (ls >= 0)
                acc += conv_w[d * D_CONV + j] *
                       b2f(xr[(size_t)(m - (D_CONV - 1) + j) * (2 * D_INNER) + d]);
        }
        short sv = f2bs(silu_f(acc));
        us[rr][d] = sv;
        *((short*)R + (size_t)m * D_INNER + d) = sv;
    }
    __syncthreads();

    int wave = t >> 6, lane = t & 63;
    for (int ni = 0; ni < 20; ni++) {
        int n = wave * 20 + ni;
        const short* wrow = (const short*)xp_wb + (size_t)n * D_INNER;
        short8 w0 = *(const short8*)(wrow + lane * 8);
        short8 w1 = *(const short8*)(wrow + lane * 8 + 512);
        short8 w2 = *(const short8*)(wrow + lane * 8 + 1024);
#pragma unroll
        for (int r = 0; r < 2; r++) {
            const short* ur = us[r];
            short8 u0 = *(const short8*)(ur + lane * 8);
            short8 u1 = *(const short8*)(ur + lane * 8 + 512);
            short8 u2 = *(const short8*)(ur + lane * 8 + 1024);
            float p = 0.f;
#pragma unroll
            for (int q = 0; q < 8; q++) {
                p += bs2f(u0[q]) * bs2f(w0[q]);
                p += bs2f(u1[q]) * bs2f(w1[q]);
                p += bs2f(u2[q]) * bs2f(w2[q]);
            }
#pragma unroll
            for (int s = 1; s < 64; s <<= 1)
                p += __shfl_xor(p, s);
            if (lane == 0)
                xdbl[(size_t)(r0 + r) * XDBL_C + n] = __float2bfloat16(p);
        }
    }
}

// Fused dt-proj + chunked scan + gate. SDG=4: 768 blocks, 64 chunks x 8 steps.
__global__ __launch_bounds__(256) void scan_fused(
    bf16* xr, const bf16* __restrict__ R, const bf16* __restrict__ xdbl,
    const bf16* __restrict__ dt_wb, const float* __restrict__ dt_b,
    const float* __restrict__ A_log, const float* __restrict__ Dp)
{
    __shared__ short us[L_SEQ][SDG + 1];
    __shared__ short dss[L_SEQ][SDG + 1];
    __shared__ float Pl[SNCH][SDG][17];
    __shared__ float Ql[SNCH][SDG][17];

    int t = threadIdx.x;
    int bg = blockIdx.x;
    int b  = bg / (D_INNER / SDG);
    int dg = bg % (D_INNER / SDG);
    int d_base = dg * SDG;

    for (int i = 0; i < L_SEQ * SDG / 256; i++) {
        int e = i * 256 + t;
        int ml = e >> 2, dl = e & 3;
        int d = d_base + dl;
        int m = b * L_SEQ + ml;
        us[ml][dl] = *((const short*)R + (size_t)m * D_INNER + d);
        const short* xrow = (const short*)xdbl + (size_t)m * XDBL_C;
        const short* wrow = (const short*)dt_wb + (size_t)d * DT_RANK;
        float acc = dt_b[d];
#pragma unroll
        for (int k8 = 0; k8 < DT_RANK / 8; k8++) {
            short8 a8 = *(const short8*)(xrow + k8 * 8);
            short8 w8 = *(const short8*)(wrow + k8 * 8);
#pragma unroll
            for (int q = 0; q < 8; q++)
                acc += bs2f(a8[q]) * bs2f(w8[q]);
        }
        acc = (acc > 20.f) ? acc : log1pf(expf(acc));
        dss[ml][dl] = f2bs(acc);
    }

    int dl_ = t & (SDG - 1);
    int c   = t >> 2;
    int d   = d_base + dl_;

    float An[D_STATE], h[D_STATE], Pp[D_STATE];
    bool chain = true;
#pragma unroll
    for (int n = 0; n < D_STATE; n++) {
        An[n] = -expf(A_log[d * D_STATE + n]);
        chain = chain && (fabsf(An[n] + (float)(n + 1)) < 1e-3f * (n + 1));
        h[n] = 0.f;
        Pp[n] = 1.f;
    }
    __syncthreads();

    int ml0 = c * SCL;
    size_t mg0 = (size_t)b * L_SEQ + ml0;

    if (chain) {
        float sdl = 0.f;
        for (int i = 0; i < SCL; i++) {
            int ml = ml0 + i;
            float dlv = bs2f(dss[ml][dl_]);
            float uvv = bs2f(us[ml][dl_]);
            float duv = dlv * uvv;
            sdl += dlv;
            const short8* brow = (const short8*)((const short*)xdbl + (mg0 + i) * XDBL_C + DT_RANK);
            short8 b0 = brow[0], b1 = brow[1];
            float e1 = expf(-dlv), ap = e1;
#pragma unroll
            for (int n = 0; n < D_STATE; n++) {
                float Bn = bs2f(n < 8 ? b0[n] : b1[n - 8]);
                h[n] = ap * h[n] + duv * Bn;
                ap *= e1;
            }
        }
        float E = expf(-sdl), Ep = E;
#pragma unroll
        for (int n = 0; n < D_STATE; n++) { Pp[n] = Ep; Ep *= E; }
    } else {
        for (int i = 0; i < SCL; i++) {
            int ml = ml0 + i;
            float dlv = bs2f(dss[ml][dl_]);
            float uvv = bs2f(us[ml][dl_]);
            float duv = dlv * uvv;
            const short8* brow = (const short8*)((const short*)xdbl + (mg0 + i) * XDBL_C + DT_RANK);
            short8 b0 = brow[0], b1 = brow[1];
#pragma unroll
            for (int n = 0; n < D_STATE; n++) {
                float a = expf(dlv * An[n]);
                Pp[n] *= a;
                float Bn = bs2f(n < 8 ? b0[n] : b1[n - 8]);
                h[n] = a * h[n] + duv * Bn;
            }
        }
    }
#pragma unroll
    for (int n = 0; n < D_STATE; n++) {
        Pl[c][dl_][n] = Pp[n];
        Ql[c][dl_][n] = h[n];
    }
    __syncthreads();

    if (t < SDG * D_STATE) {
        int dd = t & (SDG - 1);
        int nn = t >> 2;
        float h0 = 0.f;
        for (int cc = 0; cc < SNCH; cc++) {
            float p = Pl[cc][dd][nn];
            float q = Ql[cc][dd][nn];
            Pl[cc][dd][nn] = h0;
            h0 = p * h0 + q;
        }
    }
    __syncthreads();

    float Dv = Dp[d];
#pragma unroll
    for (int n = 0; n < D_STATE; n++) h[n] = Pl[c][dl_][n];
    for (int i = 0; i < SCL; i++) {
        int ml = ml0 + i;
        size_t m = mg0 + i;
        float dlv = bs2f(dss[ml][dl_]);
        float uvv = bs2f(us[ml][dl_]);
        float duv = dlv * uvv;
        const short8* brow = (const short8*)((const short*)xdbl + m * XDBL_C + DT_RANK);
        short8 b0 = brow[0], b1 = brow[1];
        short8 c0 = brow[2], c1 = brow[3];
        float y = 0.f;
        if (chain) {
            float e1 = expf(-dlv), ap = e1;
#pragma unroll
            for (int n = 0; n < D_STATE; n++) {
                float Bn = bs2f(n < 8 ? b0[n] : b1[n - 8]);
                float Cn = bs2f(n < 8 ? c0[n] : c1[n - 8]);
                h[n] = ap * h[n] + duv * Bn;
                y += h[n] * Cn;
                ap *= e1;
            }
        } else {
#pragma unroll
            for (int n = 0; n < D_STATE; n++) {
                float a = expf(dlv * An[n]);
                float Bn = bs2f(n < 8 ? b0[n] : b1[n - 8]);
                float Cn = bs2f(n < 8 ? c0[n] : c1[n - 8]);
                h[n] = a * h[n] + duv * Bn;
                y += h[n] * Cn;
            }
        }
        y += uvv * Dv;
        float r = b2f(xr[m * (2 * D_INNER) + D_INNER + d]);
        xr[m * (2 * D_INNER) + d] = __float2bfloat16(y * silu_f(r));
    }
}

__global__ __launch_bounds__(256) void embed_kernel(
    const float* __restrict__ emb, const int* __restrict__ ids,
    float* __restrict__ x, bf16* __restrict__ xb)
{
    int idx = blockIdx.x * 256 + threadIdx.x;
    if (idx >= M_ROWS * D_MODEL / 4) return;
    int m = idx / (D_MODEL / 4);
    int k4 = idx % (D_MODEL / 4);
    float4 v = ((const float4*)(emb + (size_t)ids[m] * D_MODEL))[k4];
    ((float4*)x)[idx] = v;
    short* xbs = (short*)xb + (size_t)idx * 4;
    xbs[0] = f2bs(v.x); xbs[1] = f2bs(v.y); xbs[2] = f2bs(v.z); xbs[3] = f2bs(v.w);
}

__global__ __launch_bounds__(256) void ln_kernel(
    const float* __restrict__ x, const float* __restrict__ gam,
    const float* __restrict__ bet, float* __restrict__ hidden_f32,
    bf16* __restrict__ hidden_bf)
{
    int row = blockIdx.x;
    const float* xr = x + (size_t)row * D_MODEL;
    float s = 0.f, s2 = 0.f;
    for (int i = threadIdx.x; i < D_MODEL; i += 256) {
        float v = xr[i];
        s += v; s2 += v * v;
    }
    __shared__ float red[18];
#pragma unroll
    for (int off = 32; off; off >>= 1) {
        s += __shfl_down(s, off);
        s2 += __shfl_down(s2, off);
    }
    int wid = threadIdx.x / 64, lane = threadIdx.x % 64;
    if (lane == 0) { red[wid * 2] = s; red[wid * 2 + 1] = s2; }
    __syncthreads();
    if (threadIdx.x == 0) {
        float ts = 0.f, ts2 = 0.f;
        for (int w = 0; w < 4; w++) { ts += red[w * 2]; ts2 += red[w * 2 + 1]; }
        red[16] = ts; red[17] = ts2;
    }
    __syncthreads();
    float mean = red[16] / D_MODEL;
    float var = red[17] / D_MODEL - mean * mean;
    float inv = rsqrtf(var + 1e-5f);
    for (int i = threadIdx.x; i < D_MODEL; i += 256) {
        float v = (xr[i] - mean) * inv * gam[i] + bet[i];
        hidden_f32[(size_t)row * D_MODEL + i] = v;
        hidden_bf[(size_t)row * D_MODEL + i] = __float2bfloat16(v);
    }
}

extern "C" void kernel_launch(void* const* d_in, const int* in_sizes, int n_in,
                              void* d_out, int out_size, void* d_ws, size_t ws_size,
                              hipStream_t stream) {
    const float* emb    = (const float*)d_in[0];
    const float* in_w   = (const float*)d_in[1];
    const float* conv_w = (const float*)d_in[2];
    const float* conv_b = (const float*)d_in[3];
    const float* xp_w   = (const float*)d_in[4];
    const float* dt_w   = (const float*)d_in[5];
    const float* dt_b   = (const float*)d_in[6];
    const float* A_log  = (const float*)d_in[7];
    const float* Dp     = (const float*)d_in[8];
    const float* out_w  = (const float*)d_in[9];
    const float* ln_g   = (const float*)d_in[10];
    const float* ln_b   = (const float*)d_in[11];
    const float* head_w = (const float*)d_in[12];
    const float* head_b = (const float*)d_in[13];
    const int*   ids    = (const int*)d_in[14];

    float* out_logits = (float*)d_out;
    float* out_hidden = (float*)d_out + (size_t)M_ROWS * VOCAB;

    char* base = (char*)d_ws;
    float* x       = (float*)(base);                 // 3,145,728
    bf16*  xb      = (bf16*) (base + 3145728);       // 1,572,864
    bf16*  xr      = (bf16*) (base + 4718592);       // 6,291,456
    bf16*  R       = (bf16*) (base + 11010048);      // 3,145,728
    bf16*  xdbl    = (bf16*) (base + 14155776);      //   163,840
    bf16*  hidb    = (bf16*) (base + 14319616);      // 1,572,864
    bf16*  in_wb   = (bf16*) (base + 15892480);      // 56,623,104
    bf16*  xp_wb   = (bf16*) (base + 72515584);      //  2,949,120
    bf16*  dt_wb   = (bf16*) (base + 75464704);      //  1,769,472
    bf16*  out_wb  = (bf16*) (base + 77234176);      // 28,311,552
    bf16*  head_wb = (bf16*) (base + 105545728);     //    786,432
    float* Cp      = (float*)(base + 106332160);     // 12,582,912

    // merged weight conversion: cumulative 32-elem-group ends
    {
        const int e0 = 28311552 / 32;                 // in_w
        const int e1 = e0 + 1474560 / 32;             // + xp_w
        const int e2 = e1 + 884736 / 32;              // + dt_w
        const int e3 = e2 + 14155776 / 32;            // + out_w
        const int e4 = e3 + 393216 / 32;              // + head_w
        to_bf16_all<<<(e4 + 255) / 256, 256, 0, stream>>>(
            in_w, in_wb, e0, xp_w, xp_wb, e1, dt_w, dt_wb, e2,
            out_w, out_wb, e3, head_w, head_wb, e4);
    }

    embed_kernel<<<(M_ROWS * D_MODEL / 4 + 255) / 256, 256, 0, stream>>>(emb, ids, x, xb);

    for (int i = 0; i < N_LAYERS; i++) {
        const bf16*  in_wb_i  = in_wb  + (size_t)i * 2 * D_INNER * D_MODEL;
        const float* conv_w_i = conv_w + (size_t)i * D_INNER * D_CONV;
        const float* conv_b_i = conv_b + (size_t)i * D_INNER;
        const bf16*  xp_wb_i  = xp_wb  + (size_t)i * XDBL_C * D_INNER;
        const bf16*  dt_wb_i  = dt_wb  + (size_t)i * D_INNER * DT_RANK;
        const float* dt_b_i   = dt_b   + (size_t)i * D_INNER;
        const float* A_log_i  = A_log  + (size_t)i * D_INNER * D_STATE;
        const float* Dp_i     = Dp     + (size_t)i * D_INNER;
        const bf16*  out_wb_i = out_wb + (size_t)i * D_MODEL * D_INNER;

        // 1. xr = xb @ in_w^T  (768 blocks, BK=64)
        gemm64b<<<dim3(2 * D_INNER / 64, M_ROWS / 64), 256, 0, stream>>>(
            xb, D_MODEL, in_wb_i, D_MODEL, xr, 2 * D_INNER, D_MODEL);

        // 2. fused conv+silu+xp: u -> R, xdbl  (512 blocks)
        convxp2_kernel<<<M_ROWS / 2, 256, 0, stream>>>(
            xr, conv_w_i, conv_b_i, xp_wb_i, R, xdbl);

        // 3. fused dt+scan+gate -> g into xr[:, 0:1536]  (768 blocks, SDG=4)
        scan_fused<<<B_SZ * (D_INNER / SDG), 256, 0, stream>>>(
            xr, R, xdbl, dt_wb_i, dt_b_i, A_log_i, Dp_i);

        // 4. out-proj split-K x4, BK=64  (768 blocks)
        gemm64k<<<dim3(D_MODEL / 64, M_ROWS / 64, 4), 256, 0, stream>>>(
            xr, 2 * D_INNER, out_wb_i, D_INNER, Cp, 384, D_MODEL);

        // 5. x += sum(partials); xb = bf16(x)
        reduce_out_kernel<<<(M_ROWS * D_MODEL / 4 + 255) / 256, 256, 0, stream>>>(
            Cp, x, xb);
    }

    ln_kernel<<<M_ROWS, 256, 0, stream>>>(x, ln_g, ln_b, out_hidden, hidb);

    // head split-K x2  (256 blocks)
    gemm64k<<<dim3(VOCAB / 64, M_ROWS / 64, 2), 256, 0, stream>>>(
        hidb, D_MODEL, head_wb, D_MODEL, Cp, 384, VOCAB);

    reduce_head_kernel<<<(M_ROWS * VOCAB / 4 + 255) / 256, 256, 0, stream>>>(
        Cp, head_b, out_logits);
}